// Round 5
// baseline (66.936 us; speedup 1.0000x reference)
//
#include <hip/hip_runtime.h>

typedef __attribute__((ext_vector_type(8))) short short8;
typedef __attribute__((ext_vector_type(4))) float f32x4;
typedef __attribute__((ext_vector_type(2))) float f32x2;

#define NRELROWS 502
#define NB 2048
#define DD 128
#define QPB 8
#define NBLK (NB / QPB)   // 256
#define OUT_HALF (NB * DD)

__device__ __forceinline__ short f2bf(float x) {
    union { float f; unsigned u; } c; c.f = x;
    return (short)((c.u + 0x7FFFu + ((c.u >> 16) & 1u)) >> 16);
}

// Precompute: U[r][d] = sum_f rel[r][f]*W1[d][f]
//             V[r][d] = sum_f rel[r][f]*W1[d][128+f] + b1[d]
__global__ __launch_bounds__(256) void precompute_kernel(
    const float* __restrict__ rel, const float* __restrict__ W1,
    const float* __restrict__ b1,
    float* __restrict__ U, float* __restrict__ V)
{
    const int bid = blockIdx.x;
    const int tid = threadIdx.x;
    __shared__ float srel[4][DD];
    const int r0 = bid << 2;
    for (int i = tid; i < 512; i += 256) {
        const int r = i >> 7, c = i & 127;
        const int rr = r0 + r;
        srel[r][c] = (rr < NRELROWS) ? rel[rr * DD + c] : 0.f;
    }
    __syncthreads();
    const int half = tid >> 7;      // 0 -> U, 1 -> V
    const int d = tid & 127;
    const float* wrow = W1 + d * 256 + half * 128;
    float a0 = 0.f, a1 = 0.f, a2 = 0.f, a3 = 0.f;
#pragma unroll 8
    for (int f = 0; f < 128; f += 4) {
        const float4 wv = *(const float4*)(wrow + f);
        a0 += srel[0][f]*wv.x + srel[0][f+1]*wv.y + srel[0][f+2]*wv.z + srel[0][f+3]*wv.w;
        a1 += srel[1][f]*wv.x + srel[1][f+1]*wv.y + srel[1][f+2]*wv.z + srel[1][f+3]*wv.w;
        a2 += srel[2][f]*wv.x + srel[2][f+1]*wv.y + srel[2][f+2]*wv.z + srel[2][f+3]*wv.w;
        a3 += srel[3][f]*wv.x + srel[3][f+1]*wv.y + srel[3][f+2]*wv.z + srel[3][f+3]*wv.w;
    }
    float res[4] = {a0, a1, a2, a3};
    const float bb = half ? b1[d] : 0.f;
#pragma unroll
    for (int r = 0; r < 4; ++r) {
        if (r0 + r < NRELROWS) {
            if (half) V[(r0 + r) * DD + d] = res[r] + bb;
            else      U[(r0 + r) * DD + d] = res[r];
        }
    }
}

// Persistent main: 256 blocks x 512 threads, 8 queries per block.
// Per wave: 16 attn rows. h_t reg-staged one query ahead (T14), committed to
// LDS via ds_write at iteration top. W2 fragments in LDS (lgkmcnt domain).
// Raw s_barrier (no implicit vmcnt(0)) keeps staged loads in flight.
__global__ __launch_bounds__(512) void main_kernel(
    const float* __restrict__ ent, const float* __restrict__ rel,
    const float* __restrict__ off, const float* __restrict__ b2,
    const float* __restrict__ W2,
    const int* __restrict__ anchors, const int* __restrict__ rel0,
    const int* __restrict__ p1t, const int* __restrict__ p1r,
    const float* __restrict__ U, const float* __restrict__ V,
    float* __restrict__ out)
{
    extern __shared__ float lds[];
    float* ht = lds;                                     // [128][128] f32, 64 KB
    unsigned short* w2l = (unsigned short*)(lds + DD*DD); // 32 tiles * 512 bf16, 32 KB
    float* red = (float*)(w2l + 32 * 512);               // [8][128] f32, 4 KB

    const int tid = threadIdx.x;
    const int w = tid >> 6;           // 0..7
    const int l = tid & 63;
    const int lg = l >> 4;
    const int l15 = l & 15;
    const int bq0 = blockIdx.x * QPB;

    // ---- prologue: pack W2 -> LDS in MFMA B-fragment order ----
    for (int i = tid; i < 32 * 512; i += 512) {
        const int tile = i >> 9, within = i & 511;
        const int kt = tile >> 3, nt = tile & 7;
        const int ll = within >> 3, ii = within & 7;
        const int n = nt * 16 + (ll & 15);
        const int f = kt * 32 + (ll >> 4) * 8 + ii;
        w2l[i] = (unsigned short)f2bf(W2[n * 128 + f]);
    }
    float b2v[8];
#pragma unroll
    for (int nt = 0; nt < 8; ++nt) b2v[nt] = b2[(nt << 4) + l15];

    // idx for q = 0
    const int* p1t_0 = p1t + (bq0 << 7);
    const int* p1r_0 = p1r + (bq0 << 7);
    int relA = p1r_0[(w << 4) + l15];
    int4 rr4 = *(const int4*)(p1r_0 + (w << 4) + (lg << 2));
    int aidx = anchors[bq0];
    int r0 = rel0[bq0];
    // staging loads for q = 0 (wave's rows 16w..16w+15, 8B per lane)
    f32x2 stg[16];
    {
        int4 ti[4];
#pragma unroll
        for (int j = 0; j < 4; ++j)
            ti[j] = *(const int4*)(p1t_0 + (w << 4) + (j << 2));
        int nrow[16] = {ti[0].x, ti[0].y, ti[0].z, ti[0].w,
                        ti[1].x, ti[1].y, ti[1].z, ti[1].w,
                        ti[2].x, ti[2].y, ti[2].z, ti[2].w,
                        ti[3].x, ti[3].y, ti[3].z, ti[3].w};
#pragma unroll
        for (int r = 0; r < 16; ++r)
            stg[r] = *(const f32x2*)(ent + (size_t)nrow[r] * DD + (l << 1));
    }
    // make w2l visible to all waves (raw barrier: no vmcnt drain)
    asm volatile("s_waitcnt lgkmcnt(0)" ::: "memory");
    __builtin_amdgcn_s_barrier();

#pragma unroll 1
    for (int q = 0; q < QPB; ++q) {
        const int qg = bq0 + q;
        // --- 1. commit staged rows to ht (waits exactly the staging loads) ---
#pragma unroll
        for (int r = 0; r < 16; ++r)
            *(f32x2*)(ht + (size_t)((w << 4) + r) * DD + (l << 1)) = stg[r];

        // --- 2. next-query index loads ---
        const int qn = (q + 1 < QPB) ? (q + 1) : q;
        const int* p1t_n = p1t + ((bq0 + qn) << 7);
        const int* p1r_n = p1r + ((bq0 + qn) << 7);
        int4 ti[4];
#pragma unroll
        for (int j = 0; j < 4; ++j)
            ti[j] = *(const int4*)(p1t_n + (w << 4) + (j << 2));
        const int n_relA = p1r_n[(w << 4) + l15];
        const int4 n_rr4 = *(const int4*)(p1r_n + (w << 4) + (lg << 2));
        const int n_aidx = anchors[bq0 + qn];
        const int n_r0 = rel0[bq0 + qn];

        // --- 3. q's compute loads (ALL issued before q+1 staging) ---
        const float* Vrow = V + r0 * DD;
        const float* Urow = U + relA * DD;
        short8 af[4];
#pragma unroll
        for (int kt = 0; kt < 4; ++kt) {
            const int f0 = kt * 32 + lg * 8;
            const float4 vv0 = *(const float4*)(Vrow + f0);
            const float4 vv1 = *(const float4*)(Vrow + f0 + 4);
            const float4 u0 = *(const float4*)(Urow + f0);
            const float4 u1 = *(const float4*)(Urow + f0 + 4);
            af[kt][0] = f2bf(fmaxf(u0.x + vv0.x, 0.f));
            af[kt][1] = f2bf(fmaxf(u0.y + vv0.y, 0.f));
            af[kt][2] = f2bf(fmaxf(u0.z + vv0.z, 0.f));
            af[kt][3] = f2bf(fmaxf(u0.w + vv0.w, 0.f));
            af[kt][4] = f2bf(fmaxf(u1.x + vv1.x, 0.f));
            af[kt][5] = f2bf(fmaxf(u1.y + vv1.y, 0.f));
            af[kt][6] = f2bf(fmaxf(u1.z + vv1.z, 0.f));
            af[kt][7] = f2bf(fmaxf(u1.w + vv1.w, 0.f));
        }
        const int rrk[4] = {rr4.x, rr4.y, rr4.z, rr4.w};
        float rv[8][4];
#pragma unroll
        for (int r2 = 0; r2 < 4; ++r2) {
            const float* rp = rel + rrk[r2] * DD + l15;
#pragma unroll
            for (int nt = 0; nt < 8; ++nt) rv[nt][r2] = rp[nt << 4];
        }
        const float* ar = ent + (size_t)aidx * DD + l15;
        float hav[8];
#pragma unroll
        for (int nt = 0; nt < 8; ++nt) hav[nt] = ar[nt << 4];
        const int d2 = tid & 127;
        const float o_a = ent[(size_t)aidx * DD + d2];
        const float o_r = rel[r0 * DD + d2];
        const float o_o = off[r0 * DD + d2];
        __builtin_amdgcn_sched_barrier(0);

        // --- 5. issue staging loads for q+1 (newest; stay outstanding) ---
        {
            int nrow[16] = {ti[0].x, ti[0].y, ti[0].z, ti[0].w,
                            ti[1].x, ti[1].y, ti[1].z, ti[1].w,
                            ti[2].x, ti[2].y, ti[2].z, ti[2].w,
                            ti[3].x, ti[3].y, ti[3].z, ti[3].w};
#pragma unroll
            for (int r = 0; r < 16; ++r)
                stg[r] = *(const f32x2*)(ent + (size_t)nrow[r] * DD + (l << 1));
        }
        __builtin_amdgcn_sched_barrier(0);

        // --- 6. MFMA (LDS-only operands: no vmcnt consumption) ---
        f32x4 acc[8];
#pragma unroll
        for (int nt = 0; nt < 8; ++nt) acc[nt] = (f32x4)0.f;
#pragma unroll
        for (int kt = 0; kt < 4; ++kt) {
#pragma unroll
            for (int nt = 0; nt < 8; ++nt) {
                const short8 bf = *(const short8*)(w2l + ((kt << 3) + nt) * 512 + (l << 3));
                acc[nt] = __builtin_amdgcn_mfma_f32_16x16x32_bf16(af[kt], bf, acc[nt], 0, 0, 0);
            }
        }

        // --- 8. epilogue: sum_k (attn+b2) * (ht - h_a - r_t) ---
        float psv[8];
#pragma unroll
        for (int nt = 0; nt < 8; ++nt) {
            const int d = (nt << 4) + l15;
            float p = 0.f;
#pragma unroll
            for (int r2 = 0; r2 < 4; ++r2) {
                const float at = acc[nt][r2] + b2v[nt];
                const float hv = ht[(size_t)((w << 4) + (lg << 2) + r2) * DD + d];
                p += at * (hv - hav[nt] - rv[nt][r2]);
            }
            p += __shfl_xor(p, 16);
            p += __shfl_xor(p, 32);
            psv[nt] = p;
        }

        // --- 9. cross-wave reduce + output (raw barriers, no vmcnt drain) ---
        if (lg == 0) {
#pragma unroll
            for (int nt = 0; nt < 8; ++nt)
                red[w * DD + (nt << 4) + l15] = psv[nt];
        }
        asm volatile("s_waitcnt lgkmcnt(0)" ::: "memory");
        __builtin_amdgcn_s_barrier();
        if (tid < DD) {
            float s = 0.f;
#pragma unroll
            for (int ww = 0; ww < 8; ++ww) s += red[ww * DD + tid];
            out[(qg << 7) + tid] = o_a + o_r + s;
            out[OUT_HALF + (qg << 7) + tid] = o_o;
        }
        __builtin_amdgcn_s_barrier();

        // --- 10. rotate next-query scalars ---
        relA = n_relA; rr4 = n_rr4; aidx = n_aidx; r0 = n_r0;
    }
}

extern "C" void kernel_launch(void* const* d_in, const int* in_sizes, int n_in,
                              void* d_out, int out_size, void* d_ws, size_t ws_size,
                              hipStream_t stream) {
    const float* ent  = (const float*)d_in[0];
    const float* rel  = (const float*)d_in[1];
    const float* off  = (const float*)d_in[2];
    const float* W1   = (const float*)d_in[3];
    const float* b1   = (const float*)d_in[4];
    const float* W2   = (const float*)d_in[5];
    const float* b2   = (const float*)d_in[6];
    const int* anchors = (const int*)d_in[7];
    const int* rel0    = (const int*)d_in[8];
    const int* p1t     = (const int*)d_in[9];
    const int* p1r     = (const int*)d_in[10];
    float* out = (float*)d_out;

    float* U = (float*)d_ws;                       // 502*128 f32
    float* V = U + NRELROWS * DD;                  // 502*128 f32

    const int lds_bytes = DD * DD * 4 + 32 * 512 * 2 + 8 * DD * 4;  // 102400
    hipFuncSetAttribute((const void*)main_kernel,
                        hipFuncAttributeMaxDynamicSharedMemorySize, lds_bytes);

    precompute_kernel<<<126, 256, 0, stream>>>(rel, W1, b1, U, V);
    main_kernel<<<NBLK, 512, lds_bytes, stream>>>(ent, rel, off, b2, W2,
                                                  anchors, rel0, p1t, p1r,
                                                  U, V, out);
}